// Round 1
// baseline (440.809 us; speedup 1.0000x reference)
//
#include <hip/hip_runtime.h>
#include <hip/hip_fp16.h>

#define NT 256
#define NBLK 8192
#define UN 8   // float4 batches per thread, all loads issued before compute

// True clang vector type: required for __builtin_nontemporal_load/store
// (HIP's float4 is a class type, which the builtin rejects).
typedef float f32x4 __attribute__((ext_vector_type(4)));

// Analytic replacement for the piecewise-linear SiLU LUT.
//
// Accuracy argument (vs the reference LUT interpolation, threshold 0.16):
//   - interior intervals (32 bins each): linear-interp error of silu
//     <= h^2 * max|silu''| / 8 ~= 5e-5
//   - boundary segments [-8,-6] and [6,8] are single linear spans:
//     max deviation from silu ~= 0.0026 (at x = +/-7)
//   => analytic silu(clamp(fp16(x))) matches the reference within the
//      harness threshold (measured absmax 0.03125, 5x under 0.16).
__device__ __forceinline__ float nli_silu(float xin, float lo, float hi) {
    // ref: x.half().float() — round-to-nearest-even through fp16
    float xf = __half2float(__float2half_rn(xin));
    // ref: clip to [point_reg[0], point_reg[10]] = [-8, 8]; the edge
    // overrides (y = lut[0] / lut[258]) coincide with silu(+-8) to ~1e-7.
    float xc = fminf(fmaxf(xf, lo), hi);
    // silu(x) = x / (1 + e^-x);  e^-x = 2^(-x * log2(e))
    float e = __builtin_amdgcn_exp2f(xc * -1.44269504088896340736f); // v_exp_f32
    return xc * __builtin_amdgcn_rcpf(1.0f + e);                     // v_rcp_f32
}

__global__ __launch_bounds__(NT) void nli_kernel(
    const float* __restrict__ x,
    const float* __restrict__ cut,   // point_reg, 11 entries (only [0] and [10] used)
    float* __restrict__ out,
    int n)
{
    // wave-uniform s_loads, issued once
    const float lo = cut[0];
    const float hi = cut[10];

    const int n4 = n >> 2;
    const int tid = blockIdx.x * NT + threadIdx.x;
    const int nth = gridDim.x * NT;

    const f32x4* __restrict__ x4 = (const f32x4*)x;
    f32x4* __restrict__ o4 = (f32x4*)out;

    // Benched shape: n4 = 16,777,216 = NBLK*NT*8 — exactly one batched
    // iteration of UN=8 float4 per thread, fully coalesced per instruction.
    //
    // All UN loads are issued back-to-back (8 outstanding global_load_dwordx4
    // per lane) before any compute/store — maximizes in-flight HBM bytes per
    // wave. nt flag on loads and stores: single-use streaming data, skip
    // L1/L2 allocation.
    int i = tid;
    for (; i + (UN - 1) * nth < n4; i += UN * nth) {
        f32x4 v[UN];
#pragma unroll
        for (int u = 0; u < UN; ++u)
            v[u] = __builtin_nontemporal_load(&x4[i + u * nth]);
#pragma unroll
        for (int u = 0; u < UN; ++u) {
            f32x4 r;
            r.x = nli_silu(v[u].x, lo, hi);
            r.y = nli_silu(v[u].y, lo, hi);
            r.z = nli_silu(v[u].z, lo, hi);
            r.w = nli_silu(v[u].w, lo, hi);
            __builtin_nontemporal_store(r, &o4[i + u * nth]);
        }
    }
    // float4 remainder (no-op for the benched shape)
    for (; i < n4; i += nth) {
        f32x4 v = __builtin_nontemporal_load(&x4[i]);
        f32x4 r;
        r.x = nli_silu(v.x, lo, hi);
        r.y = nli_silu(v.y, lo, hi);
        r.z = nli_silu(v.z, lo, hi);
        r.w = nli_silu(v.w, lo, hi);
        __builtin_nontemporal_store(r, &o4[i]);
    }
    // scalar tail for n % 4 != 0 (no-op for the benched shape)
    const int base = n4 << 2;
    for (int t = base + tid; t < n; t += nth) {
        out[t] = nli_silu(x[t], lo, hi);
    }
}

extern "C" void kernel_launch(void* const* d_in, const int* in_sizes, int n_in,
                              void* d_out, int out_size, void* d_ws, size_t ws_size,
                              hipStream_t stream) {
    const float* x   = (const float*)d_in[0];
    const float* cut = (const float*)d_in[1];   // point_reg, 11
    float* out = (float*)d_out;
    const int n = in_sizes[0];

    nli_kernel<<<NBLK, NT, 0, stream>>>(x, cut, out, n);
}